// Round 5
// baseline (11510.896 us; speedup 1.0000x reference)
//
#include <hip/hip_runtime.h>

#define SEQ 1024
#define NB  64
#define NI  256
#define NH  256

typedef __bf16 bf16x8 __attribute__((ext_vector_type(8)));
typedef float  f32x4  __attribute__((ext_vector_type(4)));
typedef unsigned int u32x4 __attribute__((ext_vector_type(4)));
typedef unsigned short u16;
typedef unsigned int u32;

static __device__ __forceinline__ u16 f2bf(float f) {
    u32 u = __float_as_uint(f);
    u += 0x7fffu + ((u >> 16) & 1u);
    return (u16)(u >> 16);
}
static __device__ __forceinline__ float sigm_(float x) {
    return __builtin_amdgcn_rcpf(1.0f + __builtin_amdgcn_exp2f(-1.4426950408889634f * x));
}
static __device__ __forceinline__ float tanh_(float x) {
    return 1.0f - 2.0f * __builtin_amdgcn_rcpf(__builtin_amdgcn_exp2f(2.8853900817779268f * x) + 1.0f);
}

// ---- L2-local (same-XCD) ops: sc0 = bypass L1; L1 is write-through so the
// shared XCD L2 is the serialization point for all participants. ----
static __device__ __forceinline__ void st_u32_l2(u32* p, u32 v) {
    asm volatile("global_store_dword %0, %1, off sc0" :: "v"(p), "v"(v) : "memory");
}
static __device__ __forceinline__ u32 ld_u32_l2(const u32* p) {
    u32 v;
    asm volatile("global_load_dword %0, %1, off sc0\n\ts_waitcnt vmcnt(0)"
                 : "=&v"(v) : "v"(p) : "memory");
    return v;
}
// ---- MALL-routed mirror ops (device coherence point, proven in r4) ----
static __device__ __forceinline__ void st_u32_mall(u32* p, u32 v) {
    asm volatile("global_store_dword %0, %1, off sc0 sc1" :: "v"(p), "v"(v) : "memory");
}

#define LD16_BODY(CB)                                                        \
    asm volatile(                                                            \
        "global_load_dwordx4 %0, %16, off " CB "\n\t"                        \
        "global_load_dwordx4 %1, %16, off offset:64 " CB "\n\t"              \
        "global_load_dwordx4 %2, %16, off offset:128 " CB "\n\t"             \
        "global_load_dwordx4 %3, %16, off offset:192 " CB "\n\t"             \
        "global_load_dwordx4 %4, %16, off offset:256 " CB "\n\t"             \
        "global_load_dwordx4 %5, %16, off offset:320 " CB "\n\t"             \
        "global_load_dwordx4 %6, %16, off offset:384 " CB "\n\t"             \
        "global_load_dwordx4 %7, %16, off offset:448 " CB "\n\t"             \
        "global_load_dwordx4 %8, %17, off " CB "\n\t"                        \
        "global_load_dwordx4 %9, %17, off offset:64 " CB "\n\t"              \
        "global_load_dwordx4 %10, %17, off offset:128 " CB "\n\t"            \
        "global_load_dwordx4 %11, %17, off offset:192 " CB "\n\t"            \
        "global_load_dwordx4 %12, %17, off offset:256 " CB "\n\t"            \
        "global_load_dwordx4 %13, %17, off offset:320 " CB "\n\t"            \
        "global_load_dwordx4 %14, %17, off offset:384 " CB "\n\t"            \
        "global_load_dwordx4 %15, %17, off offset:448 " CB "\n\t"            \
        "s_waitcnt vmcnt(0)"                                                 \
        : "=&v"(mf[0][0]), "=&v"(mf[0][1]), "=&v"(mf[0][2]), "=&v"(mf[0][3]),\
          "=&v"(mf[0][4]), "=&v"(mf[0][5]), "=&v"(mf[0][6]), "=&v"(mf[0][7]),\
          "=&v"(mf[1][0]), "=&v"(mf[1][1]), "=&v"(mf[1][2]), "=&v"(mf[1][3]),\
          "=&v"(mf[1][4]), "=&v"(mf[1][5]), "=&v"(mf[1][6]), "=&v"(mf[1][7]) \
        : "v"(p0), "v"(p1) : "memory")

static __device__ __forceinline__ void ld16_l2(const void* p0, const void* p1, bf16x8 mf[2][8]) {
    LD16_BODY("sc0");
}
static __device__ __forceinline__ void ld16_mall(const void* p0, const void* p1, bf16x8 mf[2][8]) {
    LD16_BODY("sc0 sc1");
}

// ctl layout (u32): [0..1] leader | [2..3] ticket | [512+g*1024 + f*16] flagL
// [2560+g*1024 + f*16] flagM  (f = role*4+wave, 0..63)
// mexL at ws+32K, mexM at ws+96K: each 2 parity x 2 group x 32x256 bf16.
__global__ __launch_bounds__(256, 1) __attribute__((amdgpu_waves_per_eu(1, 1)))
void nas_scan(const float* __restrict__ xg, const float* __restrict__ wih,
              const float* __restrict__ whh, float* __restrict__ out,
              u32* ctl, u16* mexL, u16* mexM)
{
    __shared__ __align__(16) unsigned char xbuf[32 * 512]; // [row][k] bf16, XOR-swizzled
    __shared__ float gbuf[32 * 132];                       // [row][gate*16+col], +4 pad
    __shared__ int sh_group, sh_role;

    const int t    = threadIdx.x;
    const int lane = t & 63;
    const int wave = t >> 6;

    // ---- self-organizing claim: groups bound to ONE XCD each by construction ----
    if (t == 0) {
        u32 xcc;
        asm volatile("s_getreg_b32 %0, hwreg(HW_REG_XCC_ID)" : "=s"(xcc));
        int grp = -1, rl = -1;
        for (int gq = 0; gq < 2 && grp < 0; ++gq) {
            u32 exp = 0u;
            bool won = __hip_atomic_compare_exchange_strong(
                &ctl[gq], &exp, xcc + 1u,
                __ATOMIC_ACQ_REL, __ATOMIC_ACQUIRE, __HIP_MEMORY_SCOPE_AGENT);
            u32 ldr = won ? (xcc + 1u) : exp;
            if (ldr == xcc + 1u) {
                u32 r = __hip_atomic_fetch_add(&ctl[2 + gq], 1u,
                                               __ATOMIC_RELAXED, __HIP_MEMORY_SCOPE_AGENT);
                if (r < 16u) { grp = gq; rl = (int)r; }
            }
        }
        sh_group = grp; sh_role = rl;
    }
    __syncthreads();
    const int g = sh_group;
    if (g < 0) return;                 // non-participants exit
    const int role = sh_role;
    const int c0   = role * 16;

    const int fr = lane & 15;
    const int fq = lane >> 4;

    u32* flagL = ctl + 512  + g * 1024;
    u32* flagM = ctl + 2560 + g * 1024;
    const int myf = role * 4 + wave;

    // ---- weight B-fragments -> registers, then PIN so they can't be remat'd ----
    bf16x8 wfih[2][8], wfhh[2][8];
#pragma unroll
    for (int gi = 0; gi < 2; ++gi) {
        const int gg = wave * 2 + gi;
#pragma unroll
        for (int ks = 0; ks < 8; ++ks) {
            bf16x8 a, b;
#pragma unroll
            for (int j = 0; j < 8; ++j) {
                const int idx = (gg * NH + ks * 32 + fq * 8 + j) * NH + (c0 + fr);
                a[j] = (__bf16)wih[idx];
                b[j] = (__bf16)whh[idx];
            }
            wfih[gi][ks] = a;
            wfhh[gi][ks] = b;
        }
    }
#pragma unroll
    for (int gi = 0; gi < 2; ++gi)
#pragma unroll
        for (int ks = 0; ks < 8; ++ks)
            asm volatile("" : "+v"(wfih[gi][ks]), "+v"(wfhh[gi][ks]));

    // ---- x addressing: thread covers row xr = t>>3, cols (t&7)*32..+31 ----
    const int xr  = t >> 3;
    const int xcb = (t & 7) * 32;
    const float* xbase = xg + (size_t)(g * 32 + xr) * NI + xcb;
    const unsigned sbase = (unsigned)xr * 512u + (unsigned)xcb * 2u;
    const unsigned sswz  = ((unsigned)xr & 7u) << 4;

    f32x4 xp[8];
#pragma unroll
    for (int i = 0; i < 8; ++i) xp[i] = *(const f32x4*)(xbase + i * 4);
    {
        u32 w[16];
#pragma unroll
        for (int jj = 0; jj < 16; ++jj) {
            const float a = xp[jj >> 1][(jj & 1) * 2 + 0];
            const float b = xp[jj >> 1][(jj & 1) * 2 + 1];
            w[jj] = (u32)f2bf(a) | ((u32)f2bf(b) << 16);
        }
#pragma unroll
        for (int q = 0; q < 4; ++q) {
            u32x4 W = {w[q * 4 + 0], w[q * 4 + 1], w[q * 4 + 2], w[q * 4 + 3]};
            *(u32x4*)(xbuf + ((sbase + (unsigned)q * 16u) ^ sswz)) = W;
        }
    }
    __syncthreads();

    const unsigned aswz = ((unsigned)fr & 7u) << 4;
    const unsigned ab0  = (unsigned)fr * 512u + (unsigned)fq * 16u;
    const unsigned ab1  = ab0 + 16u * 512u;

    const f32x4 fzero = {0.f, 0.f, 0.f, 0.f};
    f32x4 accx[2][2];
#pragma unroll
    for (int m = 0; m < 2; ++m)
#pragma unroll
        for (int gi = 0; gi < 2; ++gi) accx[m][gi] = fzero;
#pragma unroll
    for (int ks = 0; ks < 8; ++ks) {
        bf16x8 a0 = *(const bf16x8*)(xbuf + ((ab0 + (unsigned)ks * 64u) ^ aswz));
        bf16x8 a1 = *(const bf16x8*)(xbuf + ((ab1 + (unsigned)ks * 64u) ^ aswz));
#pragma unroll
        for (int gi = 0; gi < 2; ++gi) {
            accx[0][gi] = __builtin_amdgcn_mfma_f32_16x16x32_bf16(a0, wfih[gi][ks], accx[0][gi], 0, 0, 0);
            accx[1][gi] = __builtin_amdgcn_mfma_f32_16x16x32_bf16(a1, wfih[gi][ks], accx[1][gi], 0, 0, 0);
        }
    }
#pragma unroll
    for (int i = 0; i < 8; ++i) xp[i] = *(const f32x4*)(xbase + (size_t)(NB * NI) + i * 4);

    // per-lane A-frag base addresses into the exchange buffers
    const size_t gof = (size_t)g * 8192;
    const u16* mL0a = mexL + gof + fr * 256 + fq * 8;
    const u16* mL0b = mexL + gof + (16 + fr) * 256 + fq * 8;
    const u16* mM0a = mexM + gof + fr * 256 + fq * 8;
    const u16* mM0b = mexM + gof + (16 + fr) * 256 + fq * 8;

    const int r_own = t >> 3;
    const int cp    = t & 7;
    float cA = 0.0f, cB = 0.0f;
    bool use_fast = true;            // per-wave sticky; uniform within wave

    for (int s = 0; s < SEQ; ++s) {
        f32x4 acc[2][2];
#pragma unroll
        for (int m = 0; m < 2; ++m)
#pragma unroll
            for (int gi = 0; gi < 2; ++gi) acc[m][gi] = accx[m][gi];

        if (s > 0) {
            // ---- per-wave poll of all 64 producer-wave flags ----
            const u32 tgt = (u32)s;
            if (use_fast) {
                const u32* fl = flagL + lane * 16;
                int iters = 0;
                while (true) {
                    u32 v = ld_u32_l2(fl);
                    if (__all((int)(v >= tgt))) break;
                    if (++iters > 32768) { use_fast = false; break; } // ~insurance
                }
            }
            if (!use_fast) {
                const u32* fm = flagM + lane * 16;
                while (true) {
                    u32 v = __hip_atomic_load(fm, __ATOMIC_RELAXED, __HIP_MEMORY_SCOPE_AGENT);
                    if (__all((int)(v >= tgt))) break;
                    __builtin_amdgcn_s_sleep(1);
                }
                __builtin_amdgcn_fence(__ATOMIC_ACQUIRE, "agent");
            }

            // ---- m A-frags -> 32 MFMAs ----
            bf16x8 mf[2][8];
            const size_t pof = (size_t)(s & 1) * 16384;
            if (use_fast) ld16_l2(mL0a + pof, mL0b + pof, mf);
            else          ld16_mall(mM0a + pof, mM0b + pof, mf);
#pragma unroll
            for (int ks = 0; ks < 8; ++ks) {
#pragma unroll
                for (int gi = 0; gi < 2; ++gi) {
                    acc[0][gi] = __builtin_amdgcn_mfma_f32_16x16x32_bf16(mf[0][ks], wfhh[gi][ks], acc[0][gi], 0, 0, 0);
                    acc[1][gi] = __builtin_amdgcn_mfma_f32_16x16x32_bf16(mf[1][ks], wfhh[gi][ks], acc[1][gi], 0, 0, 0);
                }
            }
        }

        // ---- gates -> LDS (C-frag: row=(lane>>4)*4+j, col=lane&15) ----
#pragma unroll
        for (int m = 0; m < 2; ++m)
#pragma unroll
            for (int gi = 0; gi < 2; ++gi) {
                const int colw = (wave * 2 + gi) * 16 + fr;
#pragma unroll
                for (int j = 0; j < 4; ++j)
                    gbuf[(m * 16 + fq * 4 + j) * 132 + colw] = acc[m][gi][j];
            }
        __syncthreads(); // A

        // ---- NAS cell on 2 owned elements ----
        float nm0, nm1;
        {
            float nc[2], nm[2];
            const float* gb = gbuf + r_own * 132 + cp * 2;
#pragma unroll
            for (int e = 0; e < 2; ++e) {
                const float q0 = gb[0 * 16 + e], q1 = gb[1 * 16 + e], q2 = gb[2 * 16 + e], q3 = gb[3 * 16 + e];
                const float q4 = gb[4 * 16 + e], q5 = gb[5 * 16 + e], q6 = gb[6 * 16 + e], q7 = gb[7 * 16 + e];
                const float l10 = sigm_(q0);
                const float l11 = fmaxf(q1, 0.0f);
                const float l12 = sigm_(q2);
                const float l13 = fmaxf(q3, 0.0f);
                const float l14 = tanh_(q4);
                const float l15 = sigm_(q5);
                const float l16 = tanh_(q6);
                const float l17 = sigm_(q7);
                const float l20 = tanh_(l10 * l11);
                const float l21 = tanh_(l12 + l13);
                const float l22 = tanh_(l14 * l15);
                const float l23 = sigm_(l16 + l17);
                const float cold = (e == 0) ? cA : cB;
                const float l20v = tanh_(l20 + cold);
                const float ncv  = l20v * l21;
                const float l31  = tanh_(l22 + l23);
                nc[e] = ncv;
                nm[e] = tanh_(ncv * l31);
            }
            cA = nc[0]; cB = nc[1];
            nm0 = nm[0]; nm1 = nm[1];
        }

        if (s == SEQ - 1) {
            const int obase = (g * 32 + r_own) * NH + c0 + cp * 2;
            out[obase + 0] = cA + nm0;
            out[obase + 1] = cB + nm1;
        } else {
            // ---- dual-publish new_m slice; per-wave drain; per-wave flags ----
            const size_t pof = (size_t)((s + 1) & 1) * 16384;
            const size_t eoff = gof + pof + (size_t)(r_own * 256 + c0 + cp * 2);
            const u32 pk = (u32)f2bf(nm0) | ((u32)f2bf(nm1) << 16);
            st_u32_l2((u32*)(mexL + eoff), pk);
            st_u32_mall((u32*)(mexM + eoff), pk);
            asm volatile("s_waitcnt vmcnt(0)" ::: "memory"); // wave-local drain
            if (lane == 0) {
                st_u32_l2(flagL + myf * 16, (u32)(s + 1));
                __hip_atomic_store(flagM + myf * 16, (u32)(s + 1),
                                   __ATOMIC_RELAXED, __HIP_MEMORY_SCOPE_AGENT);
            }

            // ---- shadow: stage x[s+1], project through Wih, prefetch x[s+2] ----
            {
                u32 w[16];
#pragma unroll
                for (int jj = 0; jj < 16; ++jj) {
                    const float a = xp[jj >> 1][(jj & 1) * 2 + 0];
                    const float b = xp[jj >> 1][(jj & 1) * 2 + 1];
                    w[jj] = (u32)f2bf(a) | ((u32)f2bf(b) << 16);
                }
#pragma unroll
                for (int q = 0; q < 4; ++q) {
                    u32x4 W = {w[q * 4 + 0], w[q * 4 + 1], w[q * 4 + 2], w[q * 4 + 3]};
                    *(u32x4*)(xbuf + ((sbase + (unsigned)q * 16u) ^ sswz)) = W;
                }
            }
            __syncthreads(); // X
#pragma unroll
            for (int m = 0; m < 2; ++m)
#pragma unroll
                for (int gi = 0; gi < 2; ++gi) accx[m][gi] = fzero;
#pragma unroll
            for (int ks = 0; ks < 8; ++ks) {
                bf16x8 a0 = *(const bf16x8*)(xbuf + ((ab0 + (unsigned)ks * 64u) ^ aswz));
                bf16x8 a1 = *(const bf16x8*)(xbuf + ((ab1 + (unsigned)ks * 64u) ^ aswz));
#pragma unroll
                for (int gi = 0; gi < 2; ++gi) {
                    accx[0][gi] = __builtin_amdgcn_mfma_f32_16x16x32_bf16(a0, wfih[gi][ks], accx[0][gi], 0, 0, 0);
                    accx[1][gi] = __builtin_amdgcn_mfma_f32_16x16x32_bf16(a1, wfih[gi][ks], accx[1][gi], 0, 0, 0);
                }
            }
            if (s + 2 < SEQ) {
#pragma unroll
                for (int i = 0; i < 8; ++i)
                    xp[i] = *(const f32x4*)(xbase + (size_t)(s + 2) * (NB * NI) + i * 4);
            }
        }
    }
}

__global__ void nas_init(u32* ctl) {
    __hip_atomic_store(ctl + blockIdx.x * 256 + threadIdx.x, 0u,
                       __ATOMIC_RELAXED, __HIP_MEMORY_SCOPE_AGENT);
}

extern "C" void kernel_launch(void* const* d_in, const int* in_sizes, int n_in,
                              void* d_out, int out_size, void* d_ws, size_t ws_size,
                              hipStream_t stream) {
    (void)in_sizes; (void)n_in; (void)out_size; (void)ws_size;
    const float* x   = (const float*)d_in[0];
    const float* wih = (const float*)d_in[1];
    const float* whh = (const float*)d_in[2];
    float* out = (float*)d_out;

    u32* ctl  = (u32*)d_ws;                       // 32 KB control
    u16* mexL = (u16*)((char*)d_ws + 32768);      // 64 KB L2-local exchange
    u16* mexM = (u16*)((char*)d_ws + 32768 + 65536); // 64 KB MALL mirror

    nas_init<<<dim3(32), dim3(256), 0, stream>>>(ctl);
    nas_scan<<<dim3(256), dim3(256), 0, stream>>>(x, wih, whh, out, ctl, mexL, mexM);
}

// Round 6
// 5739.185 us; speedup vs baseline: 2.0057x; 2.0057x over previous
//
#include <hip/hip_runtime.h>

#define SEQ 1024
#define NB  64
#define NI  256
#define NH  256

typedef __bf16 bf16x8 __attribute__((ext_vector_type(8)));
typedef float  f32x4  __attribute__((ext_vector_type(4)));
typedef unsigned int u32x4 __attribute__((ext_vector_type(4)));
typedef unsigned short u16;
typedef unsigned int u32;

static __device__ __forceinline__ u16 f2bf(float f) {
    u32 u = __float_as_uint(f);
    u += 0x7fffu + ((u >> 16) & 1u);
    return (u16)(u >> 16);
}
static __device__ __forceinline__ float sigm_(float x) {
    return __builtin_amdgcn_rcpf(1.0f + __builtin_amdgcn_exp2f(-1.4426950408889634f * x));
}
static __device__ __forceinline__ float tanh_(float x) {
    return 1.0f - 2.0f * __builtin_amdgcn_rcpf(__builtin_amdgcn_exp2f(2.8853900817779268f * x) + 1.0f);
}

// ---- XCD-local fast path (corrected model) ----
// PLAIN store: write-through L1 -> lands DIRTY in the shared XCD L2.
// sc0-only load: bypass L1, read the shared XCD L2. Same-XCD visibility.
static __device__ __forceinline__ void st_u32_plain(u32* p, u32 v) {
    asm volatile("global_store_dword %0, %1, off" :: "v"(p), "v"(v) : "memory");
}
static __device__ __forceinline__ u32 ld_u32_l2(const u32* p) {
    u32 v;
    asm volatile("global_load_dword %0, %1, off sc0\n\ts_waitcnt vmcnt(0)"
                 : "=&v"(v) : "v"(p) : "memory");
    return v;
}
// ---- MALL mirror (proven r4 protocol) ----
static __device__ __forceinline__ void st_u32_mall(u32* p, u32 v) {
    asm volatile("global_store_dword %0, %1, off sc0 sc1" :: "v"(p), "v"(v) : "memory");
}

#define LD16_BODY(CB)                                                        \
    asm volatile(                                                            \
        "global_load_dwordx4 %0, %16, off " CB "\n\t"                        \
        "global_load_dwordx4 %1, %16, off offset:64 " CB "\n\t"              \
        "global_load_dwordx4 %2, %16, off offset:128 " CB "\n\t"             \
        "global_load_dwordx4 %3, %16, off offset:192 " CB "\n\t"             \
        "global_load_dwordx4 %4, %16, off offset:256 " CB "\n\t"             \
        "global_load_dwordx4 %5, %16, off offset:320 " CB "\n\t"             \
        "global_load_dwordx4 %6, %16, off offset:384 " CB "\n\t"             \
        "global_load_dwordx4 %7, %16, off offset:448 " CB "\n\t"             \
        "global_load_dwordx4 %8, %17, off " CB "\n\t"                        \
        "global_load_dwordx4 %9, %17, off offset:64 " CB "\n\t"              \
        "global_load_dwordx4 %10, %17, off offset:128 " CB "\n\t"            \
        "global_load_dwordx4 %11, %17, off offset:192 " CB "\n\t"            \
        "global_load_dwordx4 %12, %17, off offset:256 " CB "\n\t"            \
        "global_load_dwordx4 %13, %17, off offset:320 " CB "\n\t"            \
        "global_load_dwordx4 %14, %17, off offset:384 " CB "\n\t"            \
        "global_load_dwordx4 %15, %17, off offset:448 " CB "\n\t"            \
        "s_waitcnt vmcnt(0)"                                                 \
        : "=&v"(mf[0][0]), "=&v"(mf[0][1]), "=&v"(mf[0][2]), "=&v"(mf[0][3]),\
          "=&v"(mf[0][4]), "=&v"(mf[0][5]), "=&v"(mf[0][6]), "=&v"(mf[0][7]),\
          "=&v"(mf[1][0]), "=&v"(mf[1][1]), "=&v"(mf[1][2]), "=&v"(mf[1][3]),\
          "=&v"(mf[1][4]), "=&v"(mf[1][5]), "=&v"(mf[1][6]), "=&v"(mf[1][7]) \
        : "v"(p0), "v"(p1) : "memory")

static __device__ __forceinline__ void ld16_l2(const void* p0, const void* p1, bf16x8 mf[2][8]) {
    LD16_BODY("sc0");       // read shared XCD L2 (producers' plain stores land there)
}
static __device__ __forceinline__ void ld16_mall(const void* p0, const void* p1, bf16x8 mf[2][8]) {
    LD16_BODY("sc0 sc1");   // bypass caches -> MALL (r4-proven)
}

// ctl (u32 idx): [0..1] leader | [2..3] ticket | [4..5] init barrier |
// [512+g*1024 + f*16] flagL (f=role*4+wave, 64B apart, 256B per WG) |
// [2560+g*1024 + f*16] flagM.
// mexL at ws+32K, mexM at ws+96K: each 2 parity x 2 group x 32x256 bf16.
__global__ __launch_bounds__(256, 1) __attribute__((amdgpu_waves_per_eu(1, 1)))
void nas_scan(const float* __restrict__ xg, const float* __restrict__ wih,
              const float* __restrict__ whh, float* __restrict__ out,
              u32* ctl, u16* mexL, u16* mexM)
{
    __shared__ __align__(16) unsigned char xbuf[32 * 512]; // [row][k] bf16, XOR-swizzled
    __shared__ float gbuf[32 * 132];                       // [row][gate*16+col], +4 pad
    __shared__ int sh_group, sh_role;

    const int t    = threadIdx.x;
    const int lane = t & 63;
    const int wave = t >> 6;

    // ---- self-organizing claim: each group bound to ONE XCD by construction ----
    if (t == 0) {
        u32 xcc;
        asm volatile("s_getreg_b32 %0, hwreg(HW_REG_XCC_ID)" : "=s"(xcc));
        int grp = -1, rl = -1;
        for (int gq = 0; gq < 2 && grp < 0; ++gq) {
            u32 exp = 0u;
            bool won = __hip_atomic_compare_exchange_strong(
                &ctl[gq], &exp, xcc + 1u,
                __ATOMIC_ACQ_REL, __ATOMIC_ACQUIRE, __HIP_MEMORY_SCOPE_AGENT);
            u32 ldr = won ? (xcc + 1u) : exp;
            if (ldr == xcc + 1u) {
                u32 r = __hip_atomic_fetch_add(&ctl[2 + gq], 1u,
                                               __ATOMIC_RELAXED, __HIP_MEMORY_SCOPE_AGENT);
                if (r < 16u) { grp = gq; rl = (int)r; }
            }
        }
        sh_group = grp; sh_role = rl;
    }
    __syncthreads();
    const int g = sh_group;
    if (g < 0) return;
    const int role = sh_role;
    const int c0   = role * 16;

    const int fr = lane & 15;
    const int fq = lane >> 4;

    u32* flagL = ctl + 512  + g * 1024;
    u32* flagM = ctl + 2560 + g * 1024;
    const int myf = role * 4 + wave;

    // ---- replay-safe: re-zero OWN fast flags with PLAIN stores (updates the
    // shared L2 lines in place, killing stale values from the previous graph
    // replay), then one-time MALL barrier so no one polls before zeroing. ----
    if (t == 0) {
#pragma unroll
        for (int w = 0; w < 4; ++w)
            st_u32_plain(flagL + role * 64 + w * 16, 0u);
        asm volatile("s_waitcnt vmcnt(0)" ::: "memory");
        u32* bar = ctl + 4 + g;
        __hip_atomic_fetch_add(bar, 1u, __ATOMIC_RELEASE, __HIP_MEMORY_SCOPE_AGENT);
        while (__hip_atomic_load(bar, __ATOMIC_RELAXED, __HIP_MEMORY_SCOPE_AGENT) < 16u) {}
    }
    __syncthreads();

    // ---- weight B-fragments -> registers, pinned ----
    bf16x8 wfih[2][8], wfhh[2][8];
#pragma unroll
    for (int gi = 0; gi < 2; ++gi) {
        const int gg = wave * 2 + gi;
#pragma unroll
        for (int ks = 0; ks < 8; ++ks) {
            bf16x8 a, b;
#pragma unroll
            for (int j = 0; j < 8; ++j) {
                const int idx = (gg * NH + ks * 32 + fq * 8 + j) * NH + (c0 + fr);
                a[j] = (__bf16)wih[idx];
                b[j] = (__bf16)whh[idx];
            }
            wfih[gi][ks] = a;
            wfhh[gi][ks] = b;
        }
    }
#pragma unroll
    for (int gi = 0; gi < 2; ++gi)
#pragma unroll
        for (int ks = 0; ks < 8; ++ks)
            asm volatile("" : "+v"(wfih[gi][ks]), "+v"(wfhh[gi][ks]));

    // ---- x addressing ----
    const int xr  = t >> 3;
    const int xcb = (t & 7) * 32;
    const float* xbase = xg + (size_t)(g * 32 + xr) * NI + xcb;
    const unsigned sbase = (unsigned)xr * 512u + (unsigned)xcb * 2u;
    const unsigned sswz  = ((unsigned)xr & 7u) << 4;

    f32x4 xp[8];
#pragma unroll
    for (int i = 0; i < 8; ++i) xp[i] = *(const f32x4*)(xbase + i * 4);
    {
        u32 w[16];
#pragma unroll
        for (int jj = 0; jj < 16; ++jj) {
            const float a = xp[jj >> 1][(jj & 1) * 2 + 0];
            const float b = xp[jj >> 1][(jj & 1) * 2 + 1];
            w[jj] = (u32)f2bf(a) | ((u32)f2bf(b) << 16);
        }
#pragma unroll
        for (int q = 0; q < 4; ++q) {
            u32x4 W = {w[q * 4 + 0], w[q * 4 + 1], w[q * 4 + 2], w[q * 4 + 3]};
            *(u32x4*)(xbuf + ((sbase + (unsigned)q * 16u) ^ sswz)) = W;
        }
    }
    __syncthreads();

    const unsigned aswz = ((unsigned)fr & 7u) << 4;
    const unsigned ab0  = (unsigned)fr * 512u + (unsigned)fq * 16u;
    const unsigned ab1  = ab0 + 16u * 512u;

    const f32x4 fzero = {0.f, 0.f, 0.f, 0.f};
    f32x4 accx[2][2];
#pragma unroll
    for (int m = 0; m < 2; ++m)
#pragma unroll
        for (int gi = 0; gi < 2; ++gi) accx[m][gi] = fzero;
#pragma unroll
    for (int ks = 0; ks < 8; ++ks) {
        bf16x8 a0 = *(const bf16x8*)(xbuf + ((ab0 + (unsigned)ks * 64u) ^ aswz));
        bf16x8 a1 = *(const bf16x8*)(xbuf + ((ab1 + (unsigned)ks * 64u) ^ aswz));
#pragma unroll
        for (int gi = 0; gi < 2; ++gi) {
            accx[0][gi] = __builtin_amdgcn_mfma_f32_16x16x32_bf16(a0, wfih[gi][ks], accx[0][gi], 0, 0, 0);
            accx[1][gi] = __builtin_amdgcn_mfma_f32_16x16x32_bf16(a1, wfih[gi][ks], accx[1][gi], 0, 0, 0);
        }
    }
#pragma unroll
    for (int i = 0; i < 8; ++i) xp[i] = *(const f32x4*)(xbase + (size_t)(NB * NI) + i * 4);

    const size_t gof = (size_t)g * 8192;
    const u16* mL0a = mexL + gof + fr * 256 + fq * 8;
    const u16* mL0b = mexL + gof + (16 + fr) * 256 + fq * 8;
    const u16* mM0a = mexM + gof + fr * 256 + fq * 8;
    const u16* mM0b = mexM + gof + (16 + fr) * 256 + fq * 8;

    const int r_own = t >> 3;
    const int cp    = t & 7;
    float cA = 0.0f, cB = 0.0f;
    bool use_fast = true;   // sticky, wave-uniform

    for (int s = 0; s < SEQ; ++s) {
        f32x4 acc[2][2];
#pragma unroll
        for (int m = 0; m < 2; ++m)
#pragma unroll
            for (int gi = 0; gi < 2; ++gi) acc[m][gi] = accx[m][gi];

        if (s > 0) {
            const u32 tgt = (u32)s;
            if (use_fast) {
                const u32* fl = flagL + lane * 16;
                int iters = 0;
                while (true) {
                    u32 v = ld_u32_l2(fl);
                    if (__all((int)(v >= tgt))) break;
                    if (++iters > 4096) { use_fast = false; break; }
                }
            }
            if (!use_fast) {
                const u32* fm = flagM + lane * 16;
                while (true) {
                    u32 v = __hip_atomic_load(fm, __ATOMIC_RELAXED, __HIP_MEMORY_SCOPE_AGENT);
                    if (__all((int)(v >= tgt))) break;
                }
            }

            bf16x8 mf[2][8];
            const size_t pof = (size_t)(s & 1) * 16384;
            if (use_fast) ld16_l2(mL0a + pof, mL0b + pof, mf);
            else          ld16_mall(mM0a + pof, mM0b + pof, mf);
#pragma unroll
            for (int ks = 0; ks < 8; ++ks) {
#pragma unroll
                for (int gi = 0; gi < 2; ++gi) {
                    acc[0][gi] = __builtin_amdgcn_mfma_f32_16x16x32_bf16(mf[0][ks], wfhh[gi][ks], acc[0][gi], 0, 0, 0);
                    acc[1][gi] = __builtin_amdgcn_mfma_f32_16x16x32_bf16(mf[1][ks], wfhh[gi][ks], acc[1][gi], 0, 0, 0);
                }
            }
        }

        // ---- gates -> LDS ----
#pragma unroll
        for (int m = 0; m < 2; ++m)
#pragma unroll
            for (int gi = 0; gi < 2; ++gi) {
                const int colw = (wave * 2 + gi) * 16 + fr;
#pragma unroll
                for (int j = 0; j < 4; ++j)
                    gbuf[(m * 16 + fq * 4 + j) * 132 + colw] = acc[m][gi][j];
            }
        __syncthreads(); // A

        // ---- NAS cell ----
        float nm0, nm1;
        {
            float nc[2], nm[2];
            const float* gb = gbuf + r_own * 132 + cp * 2;
#pragma unroll
            for (int e = 0; e < 2; ++e) {
                const float q0 = gb[0 * 16 + e], q1 = gb[1 * 16 + e], q2 = gb[2 * 16 + e], q3 = gb[3 * 16 + e];
                const float q4 = gb[4 * 16 + e], q5 = gb[5 * 16 + e], q6 = gb[6 * 16 + e], q7 = gb[7 * 16 + e];
                const float l10 = sigm_(q0);
                const float l11 = fmaxf(q1, 0.0f);
                const float l12 = sigm_(q2);
                const float l13 = fmaxf(q3, 0.0f);
                const float l14 = tanh_(q4);
                const float l15 = sigm_(q5);
                const float l16 = tanh_(q6);
                const float l17 = sigm_(q7);
                const float l20 = tanh_(l10 * l11);
                const float l21 = tanh_(l12 + l13);
                const float l22 = tanh_(l14 * l15);
                const float l23 = sigm_(l16 + l17);
                const float cold = (e == 0) ? cA : cB;
                const float l20v = tanh_(l20 + cold);
                const float ncv  = l20v * l21;
                const float l31  = tanh_(l22 + l23);
                nc[e] = ncv;
                nm[e] = tanh_(ncv * l31);
            }
            cA = nc[0]; cB = nc[1];
            nm0 = nm[0]; nm1 = nm[1];
        }

        if (s == SEQ - 1) {
            const int obase = (g * 32 + r_own) * NH + c0 + cp * 2;
            out[obase + 0] = cA + nm0;
            out[obase + 1] = cB + nm1;
        } else {
            // ---- dual-publish: plain -> local L2; sc0sc1 -> MALL mirror ----
            const size_t pof = (size_t)((s + 1) & 1) * 16384;
            const size_t eoff = gof + pof + (size_t)(r_own * 256 + c0 + cp * 2);
            const u32 pk = (u32)f2bf(nm0) | ((u32)f2bf(nm1) << 16);
            st_u32_plain((u32*)(mexL + eoff), pk);
            st_u32_mall((u32*)(mexM + eoff), pk);
            asm volatile("s_waitcnt vmcnt(0)" ::: "memory"); // data done before flags
            if (lane == 0) {
                st_u32_plain(flagL + myf * 16, (u32)(s + 1));
                __hip_atomic_store(flagM + myf * 16, (u32)(s + 1),
                                   __ATOMIC_RELAXED, __HIP_MEMORY_SCOPE_AGENT);
            }

            // ---- shadow: stage x[s+1], project Wih, prefetch x[s+2] ----
            {
                u32 w[16];
#pragma unroll
                for (int jj = 0; jj < 16; ++jj) {
                    const float a = xp[jj >> 1][(jj & 1) * 2 + 0];
                    const float b = xp[jj >> 1][(jj & 1) * 2 + 1];
                    w[jj] = (u32)f2bf(a) | ((u32)f2bf(b) << 16);
                }
#pragma unroll
                for (int q = 0; q < 4; ++q) {
                    u32x4 W = {w[q * 4 + 0], w[q * 4 + 1], w[q * 4 + 2], w[q * 4 + 3]};
                    *(u32x4*)(xbuf + ((sbase + (unsigned)q * 16u) ^ sswz)) = W;
                }
            }
            __syncthreads(); // X
#pragma unroll
            for (int m = 0; m < 2; ++m)
#pragma unroll
                for (int gi = 0; gi < 2; ++gi) accx[m][gi] = fzero;
#pragma unroll
            for (int ks = 0; ks < 8; ++ks) {
                bf16x8 a0 = *(const bf16x8*)(xbuf + ((ab0 + (unsigned)ks * 64u) ^ aswz));
                bf16x8 a1 = *(const bf16x8*)(xbuf + ((ab1 + (unsigned)ks * 64u) ^ aswz));
#pragma unroll
                for (int gi = 0; gi < 2; ++gi) {
                    accx[0][gi] = __builtin_amdgcn_mfma_f32_16x16x32_bf16(a0, wfih[gi][ks], accx[0][gi], 0, 0, 0);
                    accx[1][gi] = __builtin_amdgcn_mfma_f32_16x16x32_bf16(a1, wfih[gi][ks], accx[1][gi], 0, 0, 0);
                }
            }
            if (s + 2 < SEQ) {
#pragma unroll
                for (int i = 0; i < 8; ++i)
                    xp[i] = *(const f32x4*)(xbase + (size_t)(s + 2) * (NB * NI) + i * 4);
            }
        }
    }
}

__global__ void nas_init(u32* ctl) {
    __hip_atomic_store(ctl + blockIdx.x * 256 + threadIdx.x, 0u,
                       __ATOMIC_RELAXED, __HIP_MEMORY_SCOPE_AGENT);
}

extern "C" void kernel_launch(void* const* d_in, const int* in_sizes, int n_in,
                              void* d_out, int out_size, void* d_ws, size_t ws_size,
                              hipStream_t stream) {
    (void)in_sizes; (void)n_in; (void)out_size; (void)ws_size;
    const float* x   = (const float*)d_in[0];
    const float* wih = (const float*)d_in[1];
    const float* whh = (const float*)d_in[2];
    float* out = (float*)d_out;

    u32* ctl  = (u32*)d_ws;                          // 32 KB control
    u16* mexL = (u16*)((char*)d_ws + 32768);         // 64 KB XCD-local exchange
    u16* mexM = (u16*)((char*)d_ws + 32768 + 65536); // 64 KB MALL mirror

    nas_init<<<dim3(32), dim3(256), 0, stream>>>(ctl);
    nas_scan<<<dim3(256), dim3(256), 0, stream>>>(x, wih, whh, out, ctl, mexL, mexM);
}

// Round 7
// 3365.375 us; speedup vs baseline: 3.4204x; 1.7054x over previous
//
#include <hip/hip_runtime.h>

#define SEQ 1024
#define NB  64
#define NI  256
#define NH  256

typedef __bf16 bf16x8 __attribute__((ext_vector_type(8)));
typedef float  f32x4  __attribute__((ext_vector_type(4)));
typedef unsigned int u32x4 __attribute__((ext_vector_type(4)));
typedef unsigned short u16;
typedef unsigned int u32;

static __device__ __forceinline__ u16 f2bf(float f) {
    u32 u = __float_as_uint(f);
    u += 0x7fffu + ((u >> 16) & 1u);
    return (u16)(u >> 16);
}
static __device__ __forceinline__ float sigm_(float x) {
    return __builtin_amdgcn_rcpf(1.0f + __builtin_amdgcn_exp2f(-1.4426950408889634f * x));
}
static __device__ __forceinline__ float tanh_(float x) {
    return 1.0f - 2.0f * __builtin_amdgcn_rcpf(__builtin_amdgcn_exp2f(2.8853900817779268f * x) + 1.0f);
}

// MALL-routed (device coherence point) ops — never cached in L1/L2, so no
// stale-line hazards across steps or graph replays.
static __device__ __forceinline__ void st_mall_u32(u32* p, u32 v) {
    asm volatile("global_store_dword %0, %1, off sc0 sc1" :: "v"(p), "v"(v) : "memory");
}

// 4x16B cooperative m-slice load (issue only, no wait)
#define MLOAD4(d0, d1, d2, d3, p)                                            \
    asm volatile(                                                            \
        "global_load_dwordx4 %0, %4, off sc0 sc1\n\t"                        \
        "global_load_dwordx4 %1, %4, off offset:16 sc0 sc1\n\t"              \
        "global_load_dwordx4 %2, %4, off offset:32 sc0 sc1\n\t"              \
        "global_load_dwordx4 %3, %4, off offset:48 sc0 sc1"                  \
        : "=&v"(d0), "=&v"(d1), "=&v"(d2), "=&v"(d3) : "v"(p) : "memory")

// 8x16B x-row prefetch (issue only, no wait; cacheable -> L2 reuse on the XCD)
#define PREFETCH8(dst, p)                                                    \
    asm volatile(                                                            \
        "global_load_dwordx4 %0, %8, off\n\t"                                \
        "global_load_dwordx4 %1, %8, off offset:16\n\t"                      \
        "global_load_dwordx4 %2, %8, off offset:32\n\t"                      \
        "global_load_dwordx4 %3, %8, off offset:48\n\t"                      \
        "global_load_dwordx4 %4, %8, off offset:64\n\t"                      \
        "global_load_dwordx4 %5, %8, off offset:80\n\t"                      \
        "global_load_dwordx4 %6, %8, off offset:96\n\t"                      \
        "global_load_dwordx4 %7, %8, off offset:112"                         \
        : "=&v"(dst[0]), "=&v"(dst[1]), "=&v"(dst[2]), "=&v"(dst[3]),        \
          "=&v"(dst[4]), "=&v"(dst[5]), "=&v"(dst[6]), "=&v"(dst[7])         \
        : "v"(p) : "memory")

// counted wait: m loads (4) retired, x prefetch (8) may stay in flight
#define WAIT_VM8() do {                                                      \
    asm volatile("s_waitcnt vmcnt(8)" ::: "memory");                         \
    __builtin_amdgcn_sched_barrier(0); } while (0)

// raw barrier with LDS drain only (does NOT force vmcnt(0) like __syncthreads)
#define BAR_LGKM() do {                                                      \
    asm volatile("s_waitcnt lgkmcnt(0)" ::: "memory");                       \
    __builtin_amdgcn_s_barrier();                                            \
    __builtin_amdgcn_sched_barrier(0); } while (0)

// raw barrier with FULL drain (publish stores + prefetch + LDS)
#define BAR_FULL() do {                                                      \
    asm volatile("s_waitcnt vmcnt(0) lgkmcnt(0)" ::: "memory");              \
    __builtin_amdgcn_s_barrier();                                            \
    __builtin_amdgcn_sched_barrier(0); } while (0)

// ctl (u32): [0..1] leader | [2..3] ticket | [64 + g*64 .. +15] packed flag
// line (16 WG flags in ONE 64B line per group).
// mex at ws+4KB: [parity][group][32 rows][256 cols] bf16 (16KB per slot).
__global__ __launch_bounds__(256, 1) __attribute__((amdgpu_waves_per_eu(1, 1)))
void nas_scan(const float* __restrict__ xg, const float* __restrict__ wih,
              const float* __restrict__ whh, float* __restrict__ out,
              u32* ctl, u16* mex)
{
    __shared__ __align__(16) unsigned char xbuf[32 * 512];   // x[s] bf16, swizzled
    __shared__ __align__(16) unsigned char mstage[32 * 512]; // m bf16, swizzled
    __shared__ float gbuf[32 * 133];                         // stride 133 (odd): 2-way max
    __shared__ int sh_group, sh_role;

    const int t    = threadIdx.x;
    const int lane = t & 63;
    const int wave = t >> 6;

    // ---- self-organizing XCD-co-located claim (proven r5/r6: FETCH 413->57MB) ----
    if (t == 0) {
        u32 xcc;
        asm volatile("s_getreg_b32 %0, hwreg(HW_REG_XCC_ID)" : "=s"(xcc));
        int grp = -1, rl = -1;
        for (int gq = 0; gq < 2 && grp < 0; ++gq) {
            u32 exp = 0u;
            bool won = __hip_atomic_compare_exchange_strong(
                &ctl[gq], &exp, xcc + 1u,
                __ATOMIC_ACQ_REL, __ATOMIC_ACQUIRE, __HIP_MEMORY_SCOPE_AGENT);
            u32 ldr = won ? (xcc + 1u) : exp;
            if (ldr == xcc + 1u) {
                u32 r = __hip_atomic_fetch_add(&ctl[2 + gq], 1u,
                                               __ATOMIC_RELAXED, __HIP_MEMORY_SCOPE_AGENT);
                if (r < 16u) { grp = gq; rl = (int)r; }
            }
        }
        sh_group = grp; sh_role = rl;
    }
    __syncthreads();
    const int g = sh_group;
    if (g < 0) return;
    const int role = sh_role;
    const int c0   = role * 16;

    const int fr = lane & 15;
    const int fq = lane >> 4;

    u32* fline = ctl + 64 + g * 64;   // 16 flags, one 64B line

    // ---- weight B-fragments -> registers, pinned ----
    bf16x8 wfih[2][8], wfhh[2][8];
#pragma unroll
    for (int gi = 0; gi < 2; ++gi) {
        const int gg = wave * 2 + gi;
#pragma unroll
        for (int ks = 0; ks < 8; ++ks) {
            bf16x8 a, b;
#pragma unroll
            for (int j = 0; j < 8; ++j) {
                const int idx = (gg * NH + ks * 32 + fq * 8 + j) * NH + (c0 + fr);
                a[j] = (__bf16)wih[idx];
                b[j] = (__bf16)whh[idx];
            }
            wfih[gi][ks] = a;
            wfhh[gi][ks] = b;
        }
    }
#pragma unroll
    for (int gi = 0; gi < 2; ++gi)
#pragma unroll
        for (int ks = 0; ks < 8; ++ks)
            asm volatile("" : "+v"(wfih[gi][ks]), "+v"(wfhh[gi][ks]));

    // ---- x addressing: thread covers row xr = t>>3, cols (t&7)*32..+31 ----
    const int xr  = t >> 3;
    const int xcb = (t & 7) * 32;
    const float* xbase = xg + (size_t)(g * 32 + xr) * NI + xcb;
    const unsigned sbase = (unsigned)xr * 512u + (unsigned)xcb * 2u;
    const unsigned sswz  = ((unsigned)xr & 7u) << 4;

    // stage x[0]
    f32x4 xpA[8], xpB[8];
#pragma unroll
    for (int i = 0; i < 8; ++i) xpA[i] = *(const f32x4*)(xbase + i * 4);
    {
        u32 w[16];
#pragma unroll
        for (int jj = 0; jj < 16; ++jj) {
            const float a = xpA[jj >> 1][(jj & 1) * 2 + 0];
            const float b = xpA[jj >> 1][(jj & 1) * 2 + 1];
            w[jj] = (u32)f2bf(a) | ((u32)f2bf(b) << 16);
        }
#pragma unroll
        for (int q = 0; q < 4; ++q) {
            u32x4 W = {w[q * 4 + 0], w[q * 4 + 1], w[q * 4 + 2], w[q * 4 + 3]};
            *(u32x4*)(xbuf + ((sbase + (unsigned)q * 16u) ^ sswz)) = W;
        }
    }
    __syncthreads();

    const unsigned aswz = ((unsigned)fr & 7u) << 4;
    const unsigned ab0  = (unsigned)fr * 512u + (unsigned)fq * 16u;
    const unsigned ab1  = ab0 + 16u * 512u;

    const f32x4 fzero = {0.f, 0.f, 0.f, 0.f};
    f32x4 accx[2][2];
#pragma unroll
    for (int m = 0; m < 2; ++m)
#pragma unroll
        for (int gi = 0; gi < 2; ++gi) accx[m][gi] = fzero;
#pragma unroll
    for (int ks = 0; ks < 8; ++ks) {
        bf16x8 a0 = *(const bf16x8*)(xbuf + ((ab0 + (unsigned)ks * 64u) ^ aswz));
        bf16x8 a1 = *(const bf16x8*)(xbuf + ((ab1 + (unsigned)ks * 64u) ^ aswz));
#pragma unroll
        for (int gi = 0; gi < 2; ++gi) {
            accx[0][gi] = __builtin_amdgcn_mfma_f32_16x16x32_bf16(a0, wfih[gi][ks], accx[0][gi], 0, 0, 0);
            accx[1][gi] = __builtin_amdgcn_mfma_f32_16x16x32_bf16(a1, wfih[gi][ks], accx[1][gi], 0, 0, 0);
        }
    }
    // xpA <- x[1] (plain loads; compiler inserts waits before use)
#pragma unroll
    for (int i = 0; i < 8; ++i) xpA[i] = *(const f32x4*)(xbase + (size_t)(NB * NI) + i * 4);

    const size_t gof = (size_t)g * 8192;   // u16 units
    const int r_own = t >> 3;
    const int cp    = t & 7;
    float cA = 0.0f, cB = 0.0f;

#define STEP(S_, XPC, XPN) do {                                               \
    const int s = (S_);                                                       \
    f32x4 acc[2][2];                                                          \
    _Pragma("unroll")                                                         \
    for (int m = 0; m < 2; ++m)                                               \
        _Pragma("unroll")                                                     \
        for (int gi = 0; gi < 2; ++gi) acc[m][gi] = accx[m][gi];              \
    if (s > 0) {                                                              \
        const u32 tgt = (u32)s;                                               \
        const u32* fp = fline + (lane & 15);                                  \
        for (;;) {                                                            \
            u32 v;                                                            \
            asm volatile("global_load_dword %0, %1, off sc0 sc1\n\t"          \
                         "s_waitcnt vmcnt(0)"                                 \
                         : "=&v"(v) : "v"(fp) : "memory");                    \
            if (__all((int)(v >= tgt))) break;                                \
        }                                                                     \
        f32x4 m0, m1, m2, m3;                                                 \
        const u16* mp = mex + (size_t)(s & 1) * 16384 + gof + (size_t)t * 32; \
        MLOAD4(m0, m1, m2, m3, mp);                                           \
        {                                                                     \
            const int sp = (s + 2 < SEQ) ? s + 2 : s;                         \
            const float* xq = xbase + (size_t)sp * (NB * NI);                 \
            PREFETCH8(XPN, xq);                                               \
        }                                                                     \
        WAIT_VM8();                                                           \
        {                                                                     \
            const unsigned mo  = (unsigned)t * 64u;                           \
            const unsigned msw = ((unsigned)(t >> 3) & 7u) << 4;              \
            *(f32x4*)(mstage + ((mo + 0u)  ^ msw)) = m0;                      \
            *(f32x4*)(mstage + ((mo + 16u) ^ msw)) = m1;                      \
            *(f32x4*)(mstage + ((mo + 32u) ^ msw)) = m2;                      \
            *(f32x4*)(mstage + ((mo + 48u) ^ msw)) = m3;                      \
        }                                                                     \
        BAR_LGKM();                                                           \
        _Pragma("unroll")                                                     \
        for (int ks = 0; ks < 8; ++ks) {                                      \
            bf16x8 a0 = *(const bf16x8*)(mstage + ((ab0 + (unsigned)ks * 64u) ^ aswz)); \
            bf16x8 a1 = *(const bf16x8*)(mstage + ((ab1 + (unsigned)ks * 64u) ^ aswz)); \
            _Pragma("unroll")                                                 \
            for (int gi = 0; gi < 2; ++gi) {                                  \
                acc[0][gi] = __builtin_amdgcn_mfma_f32_16x16x32_bf16(a0, wfhh[gi][ks], acc[0][gi], 0, 0, 0); \
                acc[1][gi] = __builtin_amdgcn_mfma_f32_16x16x32_bf16(a1, wfhh[gi][ks], acc[1][gi], 0, 0, 0); \
            }                                                                 \
        }                                                                     \
    } else {                                                                  \
        const float* xq = xbase + (size_t)2 * (NB * NI);                      \
        PREFETCH8(XPN, xq);                                                   \
    }                                                                         \
    _Pragma("unroll")                                                         \
    for (int m = 0; m < 2; ++m)                                               \
        _Pragma("unroll")                                                     \
        for (int gi = 0; gi < 2; ++gi) {                                      \
            const int colw = (wave * 2 + gi) * 16 + fr;                       \
            _Pragma("unroll")                                                 \
            for (int j = 0; j < 4; ++j)                                       \
                gbuf[(m * 16 + fq * 4 + j) * 133 + colw] = acc[m][gi][j];     \
        }                                                                     \
    BAR_LGKM(); /* A */                                                       \
    float nm0, nm1;                                                           \
    {                                                                         \
        float nc[2], nm[2];                                                   \
        const float* gb = gbuf + r_own * 133 + cp * 2;                        \
        _Pragma("unroll")                                                     \
        for (int e = 0; e < 2; ++e) {                                         \
            const float q0 = gb[0 * 16 + e], q1 = gb[1 * 16 + e];             \
            const float q2 = gb[2 * 16 + e], q3 = gb[3 * 16 + e];             \
            const float q4 = gb[4 * 16 + e], q5 = gb[5 * 16 + e];             \
            const float q6 = gb[6 * 16 + e], q7 = gb[7 * 16 + e];             \
            const float l10 = sigm_(q0);                                      \
            const float l11 = fmaxf(q1, 0.0f);                                \
            const float l12 = sigm_(q2);                                      \
            const float l13 = fmaxf(q3, 0.0f);                                \
            const float l14 = tanh_(q4);                                      \
            const float l15 = sigm_(q5);                                      \
            const float l16 = tanh_(q6);                                      \
            const float l17 = sigm_(q7);                                      \
            const float l20 = tanh_(l10 * l11);                               \
            const float l21 = tanh_(l12 + l13);                               \
            const float l22 = tanh_(l14 * l15);                               \
            const float l23 = sigm_(l16 + l17);                               \
            const float cold = (e == 0) ? cA : cB;                            \
            const float l20v = tanh_(l20 + cold);                             \
            const float ncv  = l20v * l21;                                    \
            const float l31  = tanh_(l22 + l23);                              \
            nc[e] = ncv;                                                      \
            nm[e] = tanh_(ncv * l31);                                         \
        }                                                                     \
        cA = nc[0]; cB = nc[1];                                               \
        nm0 = nm[0]; nm1 = nm[1];                                             \
    }                                                                         \
    if (s == SEQ - 1) {                                                       \
        const int obase = (g * 32 + r_own) * NH + c0 + cp * 2;                \
        out[obase + 0] = cA + nm0;                                            \
        out[obase + 1] = cB + nm1;                                            \
    } else {                                                                  \
        const size_t eoff = (size_t)((s + 1) & 1) * 16384 + gof               \
                          + (size_t)(r_own * 256 + c0 + cp * 2);              \
        st_mall_u32((u32*)(mex + eoff), (u32)f2bf(nm0) | ((u32)f2bf(nm1) << 16)); \
        {                                                                     \
            u32 w[16];                                                        \
            _Pragma("unroll")                                                 \
            for (int jj = 0; jj < 16; ++jj) {                                 \
                const float a = XPC[jj >> 1][(jj & 1) * 2 + 0];               \
                const float b = XPC[jj >> 1][(jj & 1) * 2 + 1];               \
                w[jj] = (u32)f2bf(a) | ((u32)f2bf(b) << 16);                  \
            }                                                                 \
            _Pragma("unroll")                                                 \
            for (int q = 0; q < 4; ++q) {                                     \
                u32x4 W = {w[q * 4 + 0], w[q * 4 + 1], w[q * 4 + 2], w[q * 4 + 3]}; \
                *(u32x4*)(xbuf + ((sbase + (unsigned)q * 16u) ^ sswz)) = W;   \
            }                                                                 \
        }                                                                     \
        BAR_FULL(); /* X: publish+prefetch drained, xbuf staged, all waves */ \
        if (t == 0)                                                           \
            st_mall_u32(fline + role, (u32)(s + 1));                          \
        _Pragma("unroll")                                                     \
        for (int m = 0; m < 2; ++m)                                           \
            _Pragma("unroll")                                                 \
            for (int gi = 0; gi < 2; ++gi) accx[m][gi] = fzero;               \
        _Pragma("unroll")                                                     \
        for (int ks = 0; ks < 8; ++ks) {                                      \
            bf16x8 a0 = *(const bf16x8*)(xbuf + ((ab0 + (unsigned)ks * 64u) ^ aswz)); \
            bf16x8 a1 = *(const bf16x8*)(xbuf + ((ab1 + (unsigned)ks * 64u) ^ aswz)); \
            _Pragma("unroll")                                                 \
            for (int gi = 0; gi < 2; ++gi) {                                  \
                accx[0][gi] = __builtin_amdgcn_mfma_f32_16x16x32_bf16(a0, wfih[gi][ks], accx[0][gi], 0, 0, 0); \
                accx[1][gi] = __builtin_amdgcn_mfma_f32_16x16x32_bf16(a1, wfih[gi][ks], accx[1][gi], 0, 0, 0); \
            }                                                                 \
        }                                                                     \
    }                                                                         \
} while (0)

    for (int sb = 0; sb < SEQ; sb += 2) {
        STEP(sb,     xpA, xpB);
        STEP(sb + 1, xpB, xpA);
    }
#undef STEP
}

__global__ void nas_init(u32* ctl) {
    u32* p = ctl + threadIdx.x;
    asm volatile("global_store_dword %0, %1, off sc0 sc1" :: "v"(p), "v"(0u) : "memory");
}

extern "C" void kernel_launch(void* const* d_in, const int* in_sizes, int n_in,
                              void* d_out, int out_size, void* d_ws, size_t ws_size,
                              hipStream_t stream) {
    (void)in_sizes; (void)n_in; (void)out_size; (void)ws_size;
    const float* x   = (const float*)d_in[0];
    const float* wih = (const float*)d_in[1];
    const float* whh = (const float*)d_in[2];
    float* out = (float*)d_out;

    u32* ctl = (u32*)d_ws;                    // 4 KB control (claim + flag lines)
    u16* mex = (u16*)((char*)d_ws + 4096);    // 64 KB m exchange

    nas_init<<<dim3(1), dim3(256), 0, stream>>>(ctl);
    nas_scan<<<dim3(256), dim3(256), 0, stream>>>(x, wih, whh, out, ctl, mex);
}